// Round 14
// baseline (135.365 us; speedup 1.0000x reference)
//
#include <hip/hip_runtime.h>
#include <math.h>

#define B_  2
#define T_  2048
#define D_  1024
#define H_  16
#define HD_ 64
#define CD_ 3072   // 3*D
#define L_  64     // chunk length
#define NC_ 32     // T/L chunks
#define TS  72     // padded LDS stride in shorts (144 B, 16B-aligned rows)
#define TT  8      // conv time-tile

typedef __attribute__((ext_vector_type(8))) short bf16x8;
typedef __attribute__((ext_vector_type(4))) float f32x4;
typedef __attribute__((ext_vector_type(4))) unsigned short u16x4;

__device__ __forceinline__ unsigned short f2bf(float f) {
    unsigned int u = __float_as_uint(f);
    unsigned int r = (u + 0x7fffu + ((u >> 16) & 1u)) >> 16;
    return (unsigned short)r;
}
__device__ __forceinline__ float bf2f(unsigned short u) {
    return __uint_as_float(((unsigned int)u) << 16);
}

// ------- one-shot fp32 -> bf16 conversion of x, W_qkv, W_z, W_out -------
__global__ __launch_bounds__(256)
void cvt_all(const float* __restrict__ x, const float* __restrict__ Wqkv,
             const float* __restrict__ Wz, const float* __restrict__ Wout,
             unsigned short* __restrict__ xb, unsigned short* __restrict__ Wqkvb,
             unsigned short* __restrict__ Wzb, unsigned short* __restrict__ Woutb) {
    int i = blockIdx.x * 256 + threadIdx.x;   // [0, 2359296)
    const float* src; unsigned short* dst; int li;
    if (i < 1048576)      { src = x;    dst = xb;    li = i; }
    else if (i < 1835008) { src = Wqkv; dst = Wqkvb; li = i - 1048576; }
    else if (i < 2097152) { src = Wz;   dst = Wzb;   li = i - 1835008; }
    else                  { src = Wout; dst = Woutb; li = i - 2097152; }
    float4 a = ((const float4*)src)[li];
    u16x4 o;
    o.x = f2bf(a.x); o.y = f2bf(a.y); o.z = f2bf(a.z); o.w = f2bf(a.w);
    ((u16x4*)dst)[li] = o;
}

// ================= 256x256-tile merged qkv+z GEMM (8 waves) =================
// A[4096,1024] x Wcat[4096,1024]^T. Grid 256 x 512 threads, 128 KiB dyn LDS.
// 2 LDS buffers, BK=64, chunk-XOR swizzle, COUNTED-vmcnt pipeline (loads stay
// in flight across barriers; never drain to 0 in the main loop).
__global__ __launch_bounds__(512, 2)
void gemm_qkvz256(const unsigned short* __restrict__ A,
                  const unsigned short* __restrict__ Bw,
                  unsigned short* __restrict__ mixedb, unsigned short* __restrict__ zb) {
    const int K = 1024;
    extern __shared__ short lds[];      // [buf:2][A:16384 | B:16384] shorts
    const int tid = threadIdx.x;
    const int bm = (blockIdx.x >> 4) * 256;
    const int bn = (blockIdx.x & 15) * 256;
    const int wid = tid >> 6;
    const int lane = tid & 63;
    const int wm = (wid >> 2) * 128;    // 2 M-wave rows
    const int wn = (wid & 3) * 64;      // 4 N-wave cols
    const int lr = lane & 15;
    const int lk = lane >> 4;

    f32x4 acc[8][4] = {};

    const int srow = tid >> 3;                       // 0..63
    const int sphys = tid & 7;
    const int sgcol = ((sphys ^ (srow & 7)) << 3);   // shorts
    const unsigned short* Ag = A + (size_t)(bm + srow) * K + sgcol;
    const unsigned short* Bg = Bw + (size_t)(bn + srow) * K + sgcol;
    short* ldsAd = lds + srow * 64 + sphys * 8;      // + bsel*32768 + j*4096
    short* ldsBd = ldsAd + 16384;

#define STG256(bsel, kt)                                                         \
    do {                                                                         \
        _Pragma("unroll")                                                        \
        for (int j = 0; j < 4; ++j) {                                            \
            __builtin_amdgcn_global_load_lds(                                    \
                (const __attribute__((address_space(1))) void*)(Ag + (size_t)(j * 64) * K + (kt) * 64), \
                (__attribute__((address_space(3))) void*)(ldsAd + (bsel) * 32768 + j * 4096), 16, 0, 0); \
            __builtin_amdgcn_global_load_lds(                                    \
                (const __attribute__((address_space(1))) void*)(Bg + (size_t)(j * 64) * K + (kt) * 64), \
                (__attribute__((address_space(3))) void*)(ldsBd + (bsel) * 32768 + j * 4096), 16, 0, 0); \
        }                                                                        \
    } while (0)

#define CMP256(bsel)                                                             \
    do {                                                                         \
        const short* LA = lds + (bsel) * 32768 + (wm + lr) * 64;                 \
        const short* LB = lds + (bsel) * 32768 + 16384 + (wn + lr) * 64;         \
        _Pragma("unroll")                                                        \
        for (int ks = 0; ks < 2; ++ks) {                                         \
            const int ch = ((ks * 4 + lk) ^ (lr & 7)) * 8;                       \
            bf16x8 bf[4], af[4];                                                 \
            _Pragma("unroll")                                                    \
            for (int ni = 0; ni < 4; ++ni) bf[ni] = *(const bf16x8*)(LB + ni * 1024 + ch); \
            _Pragma("unroll")                                                    \
            for (int mi = 0; mi < 4; ++mi) af[mi] = *(const bf16x8*)(LA + mi * 1024 + ch); \
            __builtin_amdgcn_s_setprio(1);                                       \
            _Pragma("unroll")                                                    \
            for (int mi = 0; mi < 4; ++mi)                                       \
                _Pragma("unroll")                                                \
                for (int ni = 0; ni < 4; ++ni)                                   \
                    acc[mi][ni] = __builtin_amdgcn_mfma_f32_16x16x32_bf16(       \
                        af[mi], bf[ni], acc[mi][ni], 0, 0, 0);                   \
            __builtin_amdgcn_s_setprio(0);                                       \
            _Pragma("unroll")                                                    \
            for (int mi = 0; mi < 4; ++mi) af[mi] = *(const bf16x8*)(LA + (mi + 4) * 1024 + ch); \
            __builtin_amdgcn_s_setprio(1);                                       \
            _Pragma("unroll")                                                    \
            for (int mi = 0; mi < 4; ++mi)                                       \
                _Pragma("unroll")                                                \
                for (int ni = 0; ni < 4; ++ni)                                   \
                    acc[mi + 4][ni] = __builtin_amdgcn_mfma_f32_16x16x32_bf16(   \
                        af[mi], bf[ni], acc[mi + 4][ni], 0, 0, 0);               \
            __builtin_amdgcn_s_setprio(0);                                       \
        }                                                                        \
    } while (0)

    STG256(0, 0);
    STG256(1, 1);                       // 16 loads in flight
    for (int kt = 0; kt < 16; ++kt) {
        if (kt < 15) {
            asm volatile("s_waitcnt vmcnt(8)" ::: "memory");   // tile kt landed (own)
        } else {
            asm volatile("s_waitcnt vmcnt(0)" ::: "memory");   // final drain
        }
        __builtin_amdgcn_sched_barrier(0);
        __builtin_amdgcn_s_barrier();   // all waves' tile-kt loads landed
        CMP256(kt & 1);                 // 64 MFMA/wave
        __builtin_amdgcn_s_barrier();   // all waves done reading this buffer
        if (kt < 14) STG256(kt & 1, kt + 2);   // refill freed buffer
    }

    const int r0 = lk * 4;
#pragma unroll
    for (int mi = 0; mi < 8; ++mi)
#pragma unroll
        for (int ni = 0; ni < 4; ++ni) {
            int row = bm + wm + mi * 16 + r0;
            int col = bn + wn + ni * 16 + lr;
            if (bn < 3072) {
                unsigned short* cp = mixedb + (size_t)row * 3072 + col;
#pragma unroll
                for (int r = 0; r < 4; ++r) cp[(size_t)r * 3072] = f2bf(acc[mi][ni][r]);
            } else {
                unsigned short* cp = zb + (size_t)row * 1024 + (col - 3072);
#pragma unroll
                for (int r = 0; r < 4; ++r) cp[(size_t)r * 1024] = f2bf(acc[mi][ni][r]);
            }
        }
}

// ------- final out-projection GEMM: [4096,1024]x[1024,1024]^T, fp32 C -------
// 128^2 tile, BK=64, 4 waves, XOR swizzle, counted-vmcnt pipeline.
__global__ __launch_bounds__(256, 2)
void gemm_out(const unsigned short* __restrict__ A,
              const unsigned short* __restrict__ Bw,
              float* __restrict__ C) {
    const int K = 1024, N = 1024;
    __shared__ short Ls[2][16384];      // per buf: A[128][64] | B[128][64]
    const int tid = threadIdx.x;
    const int bm = (blockIdx.x >> 3) * 128;
    const int bn = (blockIdx.x & 7) * 128;
    const int wave = tid >> 6;
    const int lane = tid & 63;
    const int wm = (wave >> 1) * 64;
    const int wn = (wave & 1) * 64;
    const int lr = lane & 15;
    const int lk = lane >> 4;

    f32x4 acc[4][4] = {};

    const int srow = tid >> 3;                       // 0..31
    const int sphys = tid & 7;
    const int sgcol = ((sphys ^ (srow & 7)) << 3);
    const unsigned short* Ag = A + (size_t)(bm + srow) * K + sgcol;
    const unsigned short* Bg = Bw + (size_t)(bn + srow) * K + sgcol;
    short* ldsAd = &Ls[0][0] + srow * 64 + sphys * 8;   // + bsel*16384 + j*2048
    short* ldsBd = ldsAd + 8192;

#define STG_O(bsel, kt)                                                          \
    do {                                                                         \
        _Pragma("unroll")                                                        \
        for (int j = 0; j < 4; ++j) {                                            \
            __builtin_amdgcn_global_load_lds(                                    \
                (const __attribute__((address_space(1))) void*)(Ag + (size_t)(j * 32) * K + (kt) * 64), \
                (__attribute__((address_space(3))) void*)(ldsAd + (bsel) * 16384 + j * 2048), 16, 0, 0); \
            __builtin_amdgcn_global_load_lds(                                    \
                (const __attribute__((address_space(1))) void*)(Bg + (size_t)(j * 32) * K + (kt) * 64), \
                (__attribute__((address_space(3))) void*)(ldsBd + (bsel) * 16384 + j * 2048), 16, 0, 0); \
        }                                                                        \
    } while (0)

#define CMP_O(bsel)                                                              \
    do {                                                                         \
        const short* LA = &Ls[bsel][0] + (wm + lr) * 64;                         \
        const short* LB = &Ls[bsel][8192] + (wn + lr) * 64;                      \
        _Pragma("unroll")                                                        \
        for (int ks = 0; ks < 2; ++ks) {                                         \
            const int ch = ((ks * 4 + lk) ^ (lr & 7)) * 8;                       \
            bf16x8 af[4], bf[4];                                                 \
            _Pragma("unroll")                                                    \
            for (int mi = 0; mi < 4; ++mi) af[mi] = *(const bf16x8*)(LA + mi * 1024 + ch); \
            _Pragma("unroll")                                                    \
            for (int ni = 0; ni < 4; ++ni) bf[ni] = *(const bf16x8*)(LB + ni * 1024 + ch); \
            __builtin_amdgcn_s_setprio(1);                                       \
            _Pragma("unroll")                                                    \
            for (int mi = 0; mi < 4; ++mi)                                       \
                _Pragma("unroll")                                                \
                for (int ni = 0; ni < 4; ++ni)                                   \
                    acc[mi][ni] = __builtin_amdgcn_mfma_f32_16x16x32_bf16(       \
                        af[mi], bf[ni], acc[mi][ni], 0, 0, 0);                   \
            __builtin_amdgcn_s_setprio(0);                                       \
        }                                                                        \
    } while (0)

    STG_O(0, 0);
    STG_O(1, 1);
    for (int kt = 0; kt < 16; ++kt) {
        if (kt < 15) {
            asm volatile("s_waitcnt vmcnt(8)" ::: "memory");
        } else {
            asm volatile("s_waitcnt vmcnt(0)" ::: "memory");
        }
        __builtin_amdgcn_sched_barrier(0);
        __builtin_amdgcn_s_barrier();
        CMP_O(kt & 1);
        __builtin_amdgcn_s_barrier();
        if (kt < 14) STG_O(kt & 1, kt + 2);
    }

    const int r0 = lk * 4;
#pragma unroll
    for (int mi = 0; mi < 4; ++mi)
#pragma unroll
        for (int ni = 0; ni < 4; ++ni) {
            float* cp = C + (size_t)(bm + wm + mi * 16 + r0) * N + bn + wn + ni * 16 + lr;
#pragma unroll
            for (int r = 0; r < 4; ++r)
                cp[(size_t)r * N] = acc[mi][ni][r];
        }
}

// ------- beta/g projection, split-K partials (fp32): 128 Mtiles x 8 Kslices -------
#define PJS 129   // padded fp32 LDS stride
__global__ __launch_bounds__(256)
void proj_bg_partial(const float* __restrict__ x, const float* __restrict__ Wb,
                     const float* __restrict__ Wa, float* __restrict__ partial) {
    const int m0 = (blockIdx.x >> 3) * 32;   // M-tile
    const int ks = blockIdx.x & 7;           // K-slice
    const int k0 = ks * 128;
    const int tid = threadIdx.x;
    __shared__ float xs[32 * PJS];
    __shared__ float wsh[32 * PJS];
    const int sr = tid >> 3;                 // 0..31
    const int sc = (tid & 7) << 4;           // 0,16,...,112
    const int mi2 = tid >> 3;
    const int n02 = (tid & 7) << 2;          // 0,4,...,28

    {
        const float* xrow = x + (size_t)(m0 + sr) * D_ + k0 + sc;
        const float* wrow = ((sr < 16) ? (Wb + (size_t)sr * D_) : (Wa + (size_t)(sr - 16) * D_)) + k0 + sc;
#pragma unroll
        for (int j = 0; j < 16; j += 4) {
            float4 a = *(const float4*)(xrow + j);
            float4 b = *(const float4*)(wrow + j);
            xs[sr * PJS + sc + j + 0] = a.x; xs[sr * PJS + sc + j + 1] = a.y;
            xs[sr * PJS + sc + j + 2] = a.z; xs[sr * PJS + sc + j + 3] = a.w;
            wsh[sr * PJS + sc + j + 0] = b.x; wsh[sr * PJS + sc + j + 1] = b.y;
            wsh[sr * PJS + sc + j + 2] = b.z; wsh[sr * PJS + sc + j + 3] = b.w;
        }
    }
    __syncthreads();

    float acc[4] = {0.f, 0.f, 0.f, 0.f};
#pragma unroll 8
    for (int kk = 0; kk < 128; ++kk) {
        float av = xs[mi2 * PJS + kk];
#pragma unroll
        for (int j = 0; j < 4; ++j)
            acc[j] = fmaf(av, wsh[(n02 + j) * PJS + kk], acc[j]);
    }
    float* op = partial + (size_t)ks * (4096 * 32) + (size_t)(m0 + mi2) * 32 + n02;
    *(float4*)op = make_float4(acc[0], acc[1], acc[2], acc[3]);
}

__global__ __launch_bounds__(256)
void proj_bg_reduce(const float* __restrict__ partial, const float* __restrict__ dt_bias,
                    const float* __restrict__ A_log,
                    float* __restrict__ beta, float* __restrict__ g) {
    const int gid = blockIdx.x * 256 + threadIdx.x;   // [0, 4096*32)
    const int m = gid >> 5;
    const int n = gid & 31;
    float s = 0.f;
#pragma unroll
    for (int ks = 0; ks < 8; ++ks)
        s += partial[(size_t)ks * (4096 * 32) + gid];
    if (n < 16) {
        beta[(size_t)m * H_ + n] = 1.f / (1.f + expf(-s));
    } else {
        int h = n - 16;
        float spin = s + dt_bias[h];
        float sp = (spin > 20.f) ? spin : log1pf(expf(spin));
        g[(size_t)m * H_ + h] = -expf(A_log[h]) * sp;
    }
}

// ---- causal depthwise conv (K=4) + SiLU: bf16 in, time-tiled x8, bf16 out ----
__global__ __launch_bounds__(256)
void conv_silu_tt(const unsigned short* __restrict__ mixedb,
                  const float* __restrict__ conv_w,
                  unsigned short* __restrict__ qkvb) {
    int idx = blockIdx.x * 256 + threadIdx.x;   // over B*(T/TT)*(CD/4)
    const int cq = idx % (CD_ / 4);
    const int bt8 = idx / (CD_ / 4);
    const int t0 = (bt8 % (T_ / TT)) * TT;
    const int b = bt8 / (T_ / TT);
    const int c0 = cq << 2;
    const unsigned short* base = mixedb + (size_t)(b * T_ + t0) * CD_ + c0;

    float vals[TT + 3][4];
#pragma unroll
    for (int i = 0; i < TT + 3; ++i) {
        int t = t0 + i - 3;
        if (t >= 0) {
            u16x4 m = *(const u16x4*)(base + (ptrdiff_t)(i - 3) * CD_);
            vals[i][0] = bf2f(m.x); vals[i][1] = bf2f(m.y);
            vals[i][2] = bf2f(m.z); vals[i][3] = bf2f(m.w);
        } else {
            vals[i][0] = vals[i][1] = vals[i][2] = vals[i][3] = 0.f;
        }
    }
    const float4* wp = (const float4*)(conv_w + (size_t)c0 * 4);
    float4 w[4] = {wp[0], wp[1], wp[2], wp[3]};

    unsigned short* outp = qkvb + (size_t)(b * T_ + t0) * CD_ + c0;
#pragma unroll
    for (int tt = 0; tt < TT; ++tt) {
        u16x4 r;
        float s0 = vals[tt + 3][0] * w[0].w + vals[tt + 2][0] * w[0].z
                 + vals[tt + 1][0] * w[0].y + vals[tt + 0][0] * w[0].x;
        float s1 = vals[tt + 3][1] * w[1].w + vals[tt + 2][1] * w[1].z
                 + vals[tt + 1][1] * w[1].y + vals[tt + 0][1] * w[1].x;
        float s2 = vals[tt + 3][2] * w[2].w + vals[tt + 2][2] * w[2].z
                 + vals[tt + 1][2] * w[2].y + vals[tt + 0][2] * w[2].x;
        float s3 = vals[tt + 3][3] * w[3].w + vals[tt + 2][3] * w[3].z
                 + vals[tt + 1][3] * w[3].y + vals[tt + 0][3] * w[3].x;
        r.x = f2bf(s0 / (1.f + expf(-s0)));
        r.y = f2bf(s1 / (1.f + expf(-s1)));
        r.z = f2bf(s2 / (1.f + expf(-s2)));
        r.w = f2bf(s3 / (1.f + expf(-s3)));
        *(u16x4*)(outp + (size_t)tt * CD_) = r;
    }
}

// ------------ phase 1 (MFMA): per-chunk dS^T[v][d], cum, a_c; k-l2norm fused --
__global__ __launch_bounds__(256)
void chunk_phase1(const unsigned short* __restrict__ qkvb,
                  const float* __restrict__ beta, const float* __restrict__ gg,
                  float* __restrict__ dST, float* __restrict__ cum,
                  float* __restrict__ ac) {
    const int cid = blockIdx.x;           // (b*H+h)*NC + c
    const int c = cid & (NC_ - 1);
    const int bh = cid >> 5;
    const int b = bh >> 4, h = bh & 15;
    const int tid = threadIdx.x;
    const int wave = tid >> 6, lane = tid & 63;
    const int t0 = c * L_;

    __shared__ __align__(16) short kT[64 * TS];   // [d][s], RAW k
    __shared__ __align__(16) short vT[64 * TS];   // [v][s], weighted (beta*decay/||k||)
    __shared__ float cumS[64], wS[64];
    __shared__ float ksumP[4][64];                // per-wave k sumsq partials

    const unsigned short* rowp = qkvb + (size_t)(b * T_ + t0 + lane) * CD_ + h * HD_ + wave * 16;
    bf16x8 k0 = *(const bf16x8*)(rowp + D_);
    bf16x8 k1 = *(const bf16x8*)(rowp + D_ + 8);
    bf16x8 v0 = *(const bf16x8*)(rowp + 2 * D_);
    bf16x8 v1 = *(const bf16x8*)(rowp + 2 * D_ + 8);

    {   // partial sum of squares of this wave's 16 k-columns for timestep s=lane
        float ks = 0.f;
#pragma unroll
        for (int j = 0; j < 8; ++j) {
            float a = bf2f((unsigned short)k0[j]); ks = fmaf(a, a, ks);
            float bq = bf2f((unsigned short)k1[j]); ks = fmaf(bq, bq, ks);
        }
        ksumP[wave][lane] = ks;
    }

    if (wave == 0) {   // parallel inclusive scan of g over the 64 timesteps
        float s = gg[(size_t)(b * T_ + t0 + lane) * H_ + h];
#pragma unroll
        for (int off = 1; off < 64; off <<= 1) {
            float up = __shfl_up(s, off, 64);
            if (lane >= off) s += up;
        }
        cumS[lane] = s;
        float cend = __shfl(s, 63, 64);
        wS[lane] = expf(cend - s) * beta[(size_t)(b * T_ + t0 + lane) * H_ + h];
        cum[(size_t)bh * T_ + t0 + lane] = s;
        if (lane == 63) ac[cid] = expf(cend);
    }
    __syncthreads();
    const float kn = rsqrtf(ksumP[0][lane] + ksumP[1][lane] + ksumP[2][lane]
                            + ksumP[3][lane] + 1e-6f);
    const float w = wS[lane] * kn;     // fold 1/||k|| into the v-weight
#pragma unroll
    for (int j = 0; j < 8; ++j) {
        kT[(wave * 16 + j) * TS + lane] = k0[j];
        kT[(wave * 16 + 8 + j) * TS + lane] = k1[j];
        vT[(wave * 16 + j) * TS + lane] = f2bf(bf2f((unsigned short)v0[j]) * w);
        vT[(wave * 16 + 8 + j) * TS + lane] = f2bf(bf2f((unsigned short)v1[j]) * w);
    }
    __syncthreads();

    const int lr = lane & 15, lk = lane >> 4;
    f32x4 acc[4] = {};
    const short* pA = vT + (wave * 16 + lr) * TS + lk * 8;
#pragma unroll
    for (int kk = 0; kk < 2; ++kk) {
        bf16x8 a = *(const bf16x8*)(pA + kk * 32);
#pragma unroll
        for (int n = 0; n < 4; ++n) {
            bf16x8 bfr = *(const bf16x8*)(kT + (n * 16 + lr) * TS + lk * 8 + kk * 32);
            acc[n] = __builtin_amdgcn_mfma_f32_16x16x32_bf16(a, bfr, acc[n], 0, 0, 0);
        }
    }
#pragma unroll
    for (int n = 0; n < 4; ++n) {
        float* op = dST + (size_t)cid * 4096 + (wave * 16 + lk * 4) * 64 + n * 16 + lr;
#pragma unroll
        for (int r = 0; r < 4; ++r)
            op[r * 64] = acc[n][r];
    }
}

// ---------------- phase 2: scan over chunks, IN PLACE (dST -> states) --------
__global__ __launch_bounds__(256)
void chunk_phase2(float* __restrict__ dST, const float* __restrict__ ac) {
    const int gid = blockIdx.x * 256 + threadIdx.x;  // B*H*4096 = 131072
    const int bh = gid >> 12;
    const int e = gid & 4095;
    float s = 0.f;
    for (int c = 0; c < NC_; ++c) {
        size_t off = (size_t)(bh * NC_ + c) * 4096 + e;
        float tmp = dST[off];
        dST[off] = s;
        s = fmaf(ac[bh * NC_ + c], s, tmp);
    }
}

// -- phase 3 (MFMA): O = exp(ct)*Q*S_in + P*V; q/k-l2norm + gated-RMSNorm fused --
__global__ __launch_bounds__(256)
void chunk_phase3(const unsigned short* __restrict__ qkvb,
                  const float* __restrict__ beta, const float* __restrict__ cum,
                  const float* __restrict__ states,   // dST layout [cid][v][d] fp32
                  const unsigned short* __restrict__ zb,
                  unsigned short* __restrict__ normb) {
    const int cid = blockIdx.x;
    const int c = cid & (NC_ - 1);
    const int bh = cid >> 5;
    const int b = bh >> 4, h = bh & 15;
    const int tid = threadIdx.x;
    const int wave = tid >> 6, lane = tid & 63;
    const int t0 = c * L_;

    __shared__ __align__(16) short vT[64 * TS];   // [v][s]
    __shared__ __align__(16) short sT[64 * TS];   // S_in^T bf16 [v][d]
    __shared__ __align__(16) short pS[64 * TS];   // P [t][s] bf16
    __shared__ float cumS[64], betaS[64];
    __shared__ float invq[64], invk[64];

    {   // stage vT (transpose)
        const unsigned short* rowp = qkvb + (size_t)(b * T_ + t0 + lane) * CD_ + 2 * D_ + h * HD_ + wave * 16;
        bf16x8 v0 = *(const bf16x8*)rowp;
        bf16x8 v1 = *(const bf16x8*)(rowp + 8);
#pragma unroll
        for (int j = 0; j < 8; ++j) {
            vT[(wave * 16 + j) * TS + lane] = v0[j];
            vT[(wave * 16 + 8 + j) * TS + lane] = v1[j];
        }
    }
    {   // stage sT (fp32 -> bf16)
        const float* sp = states + (size_t)cid * 4096 + (tid >> 2) * 64 + (tid & 3) * 16;
        short* dp = sT + (tid >> 2) * TS + (tid & 3) * 16;
#pragma unroll
        for (int j = 0; j < 16; j += 4) {
            float4 f = *(const float4*)(sp + j);
            dp[j] = f2bf(f.x); dp[j + 1] = f2bf(f.y);
            dp[j + 2] = f2bf(f.z); dp[j + 3] = f2bf(f.w);
        }
    }
    {   // per-row l2norm factors for q and k (4 threads per row)
        int row = tid >> 2;
        int seg = (tid & 3) << 4;   // 0,16,32,48
        const unsigned short* qr = qkvb + (size_t)(b * T_ + t0 + row) * CD_ + h * HD_ + seg;
        bf16x8 a0 = *(const bf16x8*)qr;
        bf16x8 a1 = *(const bf16x8*)(qr + 8);
        float sq = 0.f;
#pragma unroll
        for (int j = 0; j < 8; ++j) {
            float v = bf2f((unsigned short)a0[j]); sq = fmaf(v, v, sq);
            v = bf2f((unsigned short)a1[j]); sq = fmaf(v, v, sq);
        }
        sq += __shfl_xor(sq, 1, 64);
        sq += __shfl_xor(sq, 2, 64);
        const unsigned short* kr = qr + D_;
        bf16x8 b0 = *(const bf16x8*)kr;
        bf16x8 b1 = *(const bf16x8*)(kr + 8);
        float sk = 0.f;
#pragma unroll
        for (int j = 0; j < 8; ++j) {
            float v = bf2f((unsigned short)b0[j]); sk = fmaf(v, v, sk);
            v = bf2f((unsigned short)b1[j]); sk = fmaf(v, v, sk);
        }
        sk += __shfl_xor(sk, 1, 64);
        sk += __shfl_xor(sk, 2, 64);
        if ((tid & 3) == 0) {
            invq[row] = 0.125f * rsqrtf(sq + 1e-6f);   // includes HD^-0.5
            invk[row] = rsqrtf(sk + 1e-6f);
        }
    }
    if (tid < 64) {
        cumS[tid] = cum[(size_t)bh * T_ + t0 + tid];
        betaS[tid] = beta[(size_t)(b * T_ + t0 + tid) * H_ + h];
    }
    __syncthreads();

    const int lr = lane & 15, lk = lane >> 4;
    const unsigned short* qrow = qkvb + (size_t)(b * T_ + t0 + wave * 16 + lr) * CD_ + h * HD_;
    bf16x8 qf0 = *(const bf16x8*)(qrow + lk * 8);
    bf16x8 qf1 = *(const bf16x8*)(qrow + 32 + lk * 8);

    // QK^T on RAW q,k
    f32x4 pacc[4] = {};
#pragma unroll
    for (int n = 0; n < 4; ++n) {
        const unsigned short* krow = qkvb + (size_t)(b * T_ + t0 + n * 16 + lr) * CD_ + D_ + h * HD_;
        bf16x8 b0 = *(const bf16x8*)(krow + lk * 8);
        bf16x8 b1 = *(const bf16x8*)(krow + 32 + lk * 8);
        pacc[n] = __builtin_amdgcn_mfma_f32_16x16x32_bf16(qf0, b0, pacc[n], 0, 0, 0);
        pacc[n] = __builtin_amdgcn_mfma_f32_16x16x32_bf16(qf1, b1, pacc[n], 0, 0, 0);
    }
    // decay + mask + beta + norms -> pS (bf16)
#pragma unroll
    for (int n = 0; n < 4; ++n) {
        int s = n * 16 + lr;
        float cs = cumS[s], bsk = betaS[s] * invk[s];
#pragma unroll
        for (int r = 0; r < 4; ++r) {
            int t = wave * 16 + lk * 4 + r;
            float pv = (s <= t) ? expf(cumS[t] - cs) * bsk * pacc[n][r] * invq[t] : 0.f;
            pS[t * TS + s] = f2bf(pv);
        }
    }
    __syncthreads();

    // O = Q * S_in^T-frags (raw q, scaled after)
    f32x4 oacc[4] = {};
#pragma unroll
    for (int n = 0; n < 4; ++n) {
        const short* srow = sT + (n * 16 + lr) * TS + lk * 8;
        bf16x8 b0 = *(const bf16x8*)srow;
        bf16x8 b1 = *(const bf16x8*)(srow + 32);
        oacc[n] = __builtin_amdgcn_mfma_f32_16x16x32_bf16(qf0, b0, oacc[n], 0, 0, 0);
        oacc[n] = __builtin_amdgcn_mfma_f32_16x16x32_bf16(qf1, b1, oacc[n], 0, 0, 0);
    }
    float qsc[4];
#pragma unroll
    for (int r = 0; r < 4; ++r) {
        int t = wave * 16 + lk * 4 + r;
        qsc[r] = expf(cumS[t]) * invq[t];
    }
#pragma unroll
    for (int n = 0; n < 4; ++n)
#pragma unroll
        for (int r = 0; r < 4; ++r) oacc[n][r] *= qsc[r];
    // + P * V
    const short* prow = pS + (wave * 16 + lr) * TS + lk * 8;
    bf16x8 pf0 = *(const bf16x8*)prow;
    bf16x8 pf1 = *(const bf16x8*)(prow + 32);
#pragma unroll
    for (int n = 0; n < 4; ++n) {
        const short* vrow = vT + (n * 16 + lr) * TS + lk * 8;
        bf16x8 b0 = *(const bf16x8*)vrow;
        bf16x8 b1 = *(const bf16x8*)(vrow + 32);
        oacc[n] = __builtin_amdgcn_mfma_f32_16x16x32_bf16(pf0, b0, oacc[n], 0, 0, 0);
        oacc[n] = __builtin_amdgcn_mfma_f32_16x16x32_bf16(pf1, b1, oacc[n], 0, 0, 0);
    }

    // fused gated RMSNorm over head dim + bf16 store
#pragma unroll
    for (int r = 0; r < 4; ++r) {
        int t = wave * 16 + lk * 4 + r;
        float ss = 0.f;
#pragma unroll
        for (int n = 0; n < 4; ++n) ss = fmaf(oacc[n][r], oacc[n][r], ss);
        ss += __shfl_xor(ss, 1, 64);
        ss += __shfl_xor(ss, 2, 64);
        ss += __shfl_xor(ss, 4, 64);
        ss += __shfl_xor(ss, 8, 64);
        float inv = rsqrtf(ss * (1.f / 64.f) + 1e-6f);
        size_t rowoff = (size_t)(b * T_ + t0 + t) * D_ + h * HD_;
#pragma unroll
        for (int n = 0; n < 4; ++n) {
            float zv = bf2f(zb[rowoff + n * 16 + lr]);
            float sz = zv / (1.f + expf(-zv));
            normb[rowoff + n * 16 + lr] = f2bf(oacc[n][r] * inv * sz);
        }
    }
}

extern "C" void kernel_launch(void* const* d_in, const int* in_sizes, int n_in,
                              void* d_out, int out_size, void* d_ws, size_t ws_size,
                              hipStream_t stream) {
    const float* x       = (const float*)d_in[0];
    const float* W_qkv   = (const float*)d_in[1];
    const float* conv_w  = (const float*)d_in[2];
    const float* W_z     = (const float*)d_in[3];
    const float* W_b     = (const float*)d_in[4];
    const float* W_a     = (const float*)d_in[5];
    const float* dt_bias = (const float*)d_in[6];
    const float* A_log   = (const float*)d_in[7];
    const float* W_out   = (const float*)d_in[8];
    float* out = (float*)d_out;

    float* ws = (float*)d_ws;
    // Region A: mixedb (bf16) until conv; overlays after:
    unsigned short* mixedb = (unsigned short*)ws;              // 12.6M bf16 (25 MB)
    float* dST    = ws;                        // 4M floats (ph1 -> ph2 in-place -> ph3)
    unsigned short* normb = (unsigned short*)(ws + 4194304);   // 4.2M bf16 (ph3 output)
    float* betab  = ws + 8388608;              // 65,536
    float* gb     = ws + 8454144;              // 65,536
    float* cum    = ws + 8519680;              // 65,536
    float* ac     = ws + 8585216;              // 1,024
    unsigned short* Woutb = (unsigned short*)(ws + 8586240);   // 1M bf16
    // Region B: xb/Wqkvb/Wzb pre-conv; qkvb after
    unsigned short* xb    = (unsigned short*)(ws + 12582912);  // 4M bf16
    unsigned short* Wqkvb = (unsigned short*)(ws + 14680064);  // 3M bf16 (cat head)
    unsigned short* Wzb   = (unsigned short*)(ws + 16252928);  // 1M bf16 (cat tail)
    unsigned short* qkvb  = (unsigned short*)(ws + 12582912);  // 12.6M bf16
    // Region C
    unsigned short* zb    = (unsigned short*)(ws + 18874368);  // 4M bf16
    float* bgpart = ws + 23068672;             // 1M floats (4 MB)

    const int M = B_ * T_;                     // 4096
    dim3 blk(256);

    cvt_all<<<dim3(9216), blk, 0, stream>>>(x, W_qkv, W_z, W_out, xb, Wqkvb, Wzb, Woutb);

    gemm_qkvz256<<<dim3(256), dim3(512), 131072, stream>>>(xb, Wqkvb, mixedb, zb);

    conv_silu_tt<<<dim3(B_ * (T_ / TT) * (CD_ / 4) / 256), blk, 0, stream>>>(mixedb, conv_w, qkvb);

    proj_bg_partial<<<dim3(1024), blk, 0, stream>>>(x, W_b, W_a, bgpart);
    proj_bg_reduce<<<dim3(512), blk, 0, stream>>>(bgpart, dt_bias, A_log, betab, gb);

    chunk_phase1<<<dim3(B_ * H_ * NC_), blk, 0, stream>>>(qkvb, betab, gb, dST, cum, ac);
    chunk_phase2<<<dim3(B_ * H_ * 4096 / 256), blk, 0, stream>>>(dST, ac);
    chunk_phase3<<<dim3(B_ * H_ * NC_), blk, 0, stream>>>(qkvb, betab, cum, dST, zb, normb);

    gemm_out<<<dim3(256), blk, 0, stream>>>(normb, Woutb, out);
}

// Round 15
// 133.996 us; speedup vs baseline: 1.0102x; 1.0102x over previous
//
#include <hip/hip_runtime.h>
#include <math.h>

#define B_  2
#define T_  2048
#define D_  1024
#define H_  16
#define HD_ 64
#define CD_ 3072   // 3*D
#define L_  64     // chunk length
#define NC_ 32     // T/L chunks
#define TS  72     // padded LDS stride in shorts (144 B, 16B-aligned rows)
#define TT  8      // conv time-tile

typedef __attribute__((ext_vector_type(8))) short bf16x8;
typedef __attribute__((ext_vector_type(4))) float f32x4;
typedef __attribute__((ext_vector_type(4))) unsigned short u16x4;

__device__ __forceinline__ unsigned short f2bf(float f) {
    unsigned int u = __float_as_uint(f);
    unsigned int r = (u + 0x7fffu + ((u >> 16) & 1u)) >> 16;
    return (unsigned short)r;
}
__device__ __forceinline__ float bf2f(unsigned short u) {
    return __uint_as_float(((unsigned int)u) << 16);
}

// ------- one-shot fp32 -> bf16 conversion of x, W_qkv, W_z, W_out -------
__global__ __launch_bounds__(256)
void cvt_all(const float* __restrict__ x, const float* __restrict__ Wqkv,
             const float* __restrict__ Wz, const float* __restrict__ Wout,
             unsigned short* __restrict__ xb, unsigned short* __restrict__ Wqkvb,
             unsigned short* __restrict__ Wzb, unsigned short* __restrict__ Woutb) {
    int i = blockIdx.x * 256 + threadIdx.x;   // [0, 2359296)
    const float* src; unsigned short* dst; int li;
    if (i < 1048576)      { src = x;    dst = xb;    li = i; }
    else if (i < 1835008) { src = Wqkv; dst = Wqkvb; li = i - 1048576; }
    else if (i < 2097152) { src = Wz;   dst = Wzb;   li = i - 1835008; }
    else                  { src = Wout; dst = Woutb; li = i - 2097152; }
    float4 a = ((const float4*)src)[li];
    u16x4 o;
    o.x = f2bf(a.x); o.y = f2bf(a.y); o.z = f2bf(a.z); o.w = f2bf(a.w);
    ((u16x4*)dst)[li] = o;
}

// ================= 256x256-tile merged qkv+z GEMM, 8-PHASE =================
// A[4096,1024] x Wcat[4096,1024]^T. 256 blocks x 512 threads, 128 KiB dyn LDS.
// Per K-tile: 4 phases of {8 ds_read + 1 half-tile stage (2 gload_lds) +
// setprio-wrapped 16 MFMA + barrier}. Loads for tile t+1 spread across tile
// t's phases; vmcnt(0)+barrier once per tile (only t's loads outstanding).
__global__ __launch_bounds__(512, 2)
void gemm_qkvz256(const unsigned short* __restrict__ A,
                  const unsigned short* __restrict__ Bw,
                  unsigned short* __restrict__ mixedb, unsigned short* __restrict__ zb) {
    const int K = 1024;
    extern __shared__ short lds[];      // [buf:2][A:16384 | B:16384] shorts
    const int tid = threadIdx.x;
    const int bm = (blockIdx.x >> 4) * 256;
    const int bn = (blockIdx.x & 15) * 256;
    const int wid = tid >> 6;
    const int lane = tid & 63;
    const int wm = (wid >> 2) * 128;    // 2 M-wave rows
    const int wn = (wid & 3) * 64;      // 4 N-wave cols
    const int lr = lane & 15;
    const int lk = lane >> 4;

    f32x4 acc[8][4] = {};

    const int srow = tid >> 3;                       // 0..63
    const int sphys = tid & 7;
    const int sgcol = ((sphys ^ (srow & 7)) << 3);   // shorts
    const unsigned short* Ag = A + (size_t)(bm + srow) * K + sgcol;
    const unsigned short* Bg = Bw + (size_t)(bn + srow) * K + sgcol;
    short* ldsAd = lds + srow * 64 + sphys * 8;      // + bsel*32768 + j*4096
    short* ldsBd = ldsAd + 16384;

    // stage 2 j-chunks (j0, j0+1) of A or B for K-tile kt into buffer bsel
#define SA2(bsel, kt, j0)                                                        \
    do {                                                                         \
        _Pragma("unroll")                                                        \
        for (int jj = (j0); jj < (j0) + 2; ++jj)                                 \
            __builtin_amdgcn_global_load_lds(                                    \
                (const __attribute__((address_space(1))) void*)(Ag + (size_t)(jj * 64) * K + (kt) * 64), \
                (__attribute__((address_space(3))) void*)(ldsAd + (bsel) * 32768 + jj * 4096), 16, 0, 0); \
    } while (0)
#define SB2(bsel, kt, j0)                                                        \
    do {                                                                         \
        _Pragma("unroll")                                                        \
        for (int jj = (j0); jj < (j0) + 2; ++jj)                                 \
            __builtin_amdgcn_global_load_lds(                                    \
                (const __attribute__((address_space(1))) void*)(Bg + (size_t)(jj * 64) * K + (kt) * 64), \
                (__attribute__((address_space(3))) void*)(ldsBd + (bsel) * 32768 + jj * 4096), 16, 0, 0); \
    } while (0)

    // prologue: fully stage K-tile 0 into buf 0 (8 loads in flight)
    SA2(0, 0, 0); SB2(0, 0, 0); SA2(0, 0, 2); SB2(0, 0, 2);

    for (int kt = 0; kt < 16; ++kt) {
        const int cur = kt & 1;
        const int nb = cur ^ 1;
        asm volatile("s_waitcnt vmcnt(0)" ::: "memory");  // tile kt landed (t+1 not issued yet)
        __builtin_amdgcn_sched_barrier(0);
        __builtin_amdgcn_s_barrier();                     // all waves' loads landed
        const short* LA = lds + cur * 32768 + (wm + lr) * 64;
        const short* LB = lds + cur * 32768 + 16384 + (wn + lr) * 64;
        bf16x8 bf[4], af[4];
        const int ch0 = (lk ^ (lr & 7)) * 8;
        const int ch1 = ((4 + lk) ^ (lr & 7)) * 8;

        // ---- phase 1: ks=0, mi 0-3 ----
#pragma unroll
        for (int ni = 0; ni < 4; ++ni) bf[ni] = *(const bf16x8*)(LB + ni * 1024 + ch0);
#pragma unroll
        for (int mi = 0; mi < 4; ++mi) af[mi] = *(const bf16x8*)(LA + mi * 1024 + ch0);
        if (kt < 15) SA2(nb, kt + 1, 0);
        __builtin_amdgcn_s_setprio(1);
#pragma unroll
        for (int mi = 0; mi < 4; ++mi)
#pragma unroll
            for (int ni = 0; ni < 4; ++ni)
                acc[mi][ni] = __builtin_amdgcn_mfma_f32_16x16x32_bf16(
                    af[mi], bf[ni], acc[mi][ni], 0, 0, 0);
        __builtin_amdgcn_s_setprio(0);
        __builtin_amdgcn_s_barrier();

        // ---- phase 2: ks=0, mi 4-7 ----
#pragma unroll
        for (int mi = 0; mi < 4; ++mi) af[mi] = *(const bf16x8*)(LA + (mi + 4) * 1024 + ch0);
        if (kt < 15) SB2(nb, kt + 1, 0);
        __builtin_amdgcn_s_setprio(1);
#pragma unroll
        for (int mi = 0; mi < 4; ++mi)
#pragma unroll
            for (int ni = 0; ni < 4; ++ni)
                acc[mi + 4][ni] = __builtin_amdgcn_mfma_f32_16x16x32_bf16(
                    af[mi], bf[ni], acc[mi + 4][ni], 0, 0, 0);
        __builtin_amdgcn_s_setprio(0);
        __builtin_amdgcn_s_barrier();

        // ---- phase 3: ks=1, mi 0-3 ----
#pragma unroll
        for (int ni = 0; ni < 4; ++ni) bf[ni] = *(const bf16x8*)(LB + ni * 1024 + ch1);
#pragma unroll
        for (int mi = 0; mi < 4; ++mi) af[mi] = *(const bf16x8*)(LA + mi * 1024 + ch1);
        if (kt < 15) SA2(nb, kt + 1, 2);
        __builtin_amdgcn_s_setprio(1);
#pragma unroll
        for (int mi = 0; mi < 4; ++mi)
#pragma unroll
            for (int ni = 0; ni < 4; ++ni)
                acc[mi][ni] = __builtin_amdgcn_mfma_f32_16x16x32_bf16(
                    af[mi], bf[ni], acc[mi][ni], 0, 0, 0);
        __builtin_amdgcn_s_setprio(0);
        __builtin_amdgcn_s_barrier();

        // ---- phase 4: ks=1, mi 4-7 ----
#pragma unroll
        for (int mi = 0; mi < 4; ++mi) af[mi] = *(const bf16x8*)(LA + (mi + 4) * 1024 + ch1);
        if (kt < 15) SB2(nb, kt + 1, 2);
        __builtin_amdgcn_s_setprio(1);
#pragma unroll
        for (int mi = 0; mi < 4; ++mi)
#pragma unroll
            for (int ni = 0; ni < 4; ++ni)
                acc[mi + 4][ni] = __builtin_amdgcn_mfma_f32_16x16x32_bf16(
                    af[mi], bf[ni], acc[mi + 4][ni], 0, 0, 0);
        __builtin_amdgcn_s_setprio(0);
        __builtin_amdgcn_s_barrier();                     // end of tile: buf cur free
    }

    const int r0 = lk * 4;
#pragma unroll
    for (int mi = 0; mi < 8; ++mi)
#pragma unroll
        for (int ni = 0; ni < 4; ++ni) {
            int row = bm + wm + mi * 16 + r0;
            int col = bn + wn + ni * 16 + lr;
            if (bn < 3072) {
                unsigned short* cp = mixedb + (size_t)row * 3072 + col;
#pragma unroll
                for (int r = 0; r < 4; ++r) cp[(size_t)r * 3072] = f2bf(acc[mi][ni][r]);
            } else {
                unsigned short* cp = zb + (size_t)row * 1024 + (col - 3072);
#pragma unroll
                for (int r = 0; r < 4; ++r) cp[(size_t)r * 1024] = f2bf(acc[mi][ni][r]);
            }
        }
}

// ------- final out-projection GEMM: [4096,1024]x[1024,1024]^T, fp32 C -------
// 128^2 tile, BK=64, 4 waves, XOR swizzle, syncthreads double-buffer (r13 form).
__global__ __launch_bounds__(256, 2)
void gemm_out(const unsigned short* __restrict__ A,
              const unsigned short* __restrict__ Bw,
              float* __restrict__ C) {
    const int K = 1024, N = 1024;
    __shared__ short Ls[2][16384];      // per buf: A[128][64] | B[128][64]
    const int tid = threadIdx.x;
    const int bm = (blockIdx.x >> 3) * 128;
    const int bn = (blockIdx.x & 7) * 128;
    const int wave = tid >> 6;
    const int lane = tid & 63;
    const int wm = (wave >> 1) * 64;
    const int wn = (wave & 1) * 64;
    const int lr = lane & 15;
    const int lk = lane >> 4;

    f32x4 acc[4][4] = {};

    const int srow = tid >> 3;                       // 0..31
    const int sphys = tid & 7;
    const int sgcol = ((sphys ^ (srow & 7)) << 3);
    const unsigned short* Ag = A + (size_t)(bm + srow) * K + sgcol;
    const unsigned short* Bg = Bw + (size_t)(bn + srow) * K + sgcol;
    short* ldsAd = &Ls[0][0] + srow * 64 + sphys * 8;   // + bsel*16384 + j*2048
    short* ldsBd = ldsAd + 8192;

#define STG_O(bsel, kt)                                                          \
    do {                                                                         \
        _Pragma("unroll")                                                        \
        for (int j = 0; j < 4; ++j) {                                            \
            __builtin_amdgcn_global_load_lds(                                    \
                (const __attribute__((address_space(1))) void*)(Ag + (size_t)(j * 32) * K + (kt) * 64), \
                (__attribute__((address_space(3))) void*)(ldsAd + (bsel) * 16384 + j * 2048), 16, 0, 0); \
            __builtin_amdgcn_global_load_lds(                                    \
                (const __attribute__((address_space(1))) void*)(Bg + (size_t)(j * 32) * K + (kt) * 64), \
                (__attribute__((address_space(3))) void*)(ldsBd + (bsel) * 16384 + j * 2048), 16, 0, 0); \
        }                                                                        \
    } while (0)

#define CMP_O(bsel)                                                              \
    do {                                                                         \
        const short* LA = &Ls[bsel][0] + (wm + lr) * 64;                         \
        const short* LB = &Ls[bsel][8192] + (wn + lr) * 64;                      \
        _Pragma("unroll")                                                        \
        for (int ks = 0; ks < 2; ++ks) {                                         \
            const int ch = ((ks * 4 + lk) ^ (lr & 7)) * 8;                       \
            bf16x8 af[4], bf[4];                                                 \
            _Pragma("unroll")                                                    \
            for (int mi = 0; mi < 4; ++mi) af[mi] = *(const bf16x8*)(LA + mi * 1024 + ch); \
            _Pragma("unroll")                                                    \
            for (int ni = 0; ni < 4; ++ni) bf[ni] = *(const bf16x8*)(LB + ni * 1024 + ch); \
            __builtin_amdgcn_s_setprio(1);                                       \
            _Pragma("unroll")                                                    \
            for (int mi = 0; mi < 4; ++mi)                                       \
                _Pragma("unroll")                                                \
                for (int ni = 0; ni < 4; ++ni)                                   \
                    acc[mi][ni] = __builtin_amdgcn_mfma_f32_16x16x32_bf16(       \
                        af[mi], bf[ni], acc[mi][ni], 0, 0, 0);                   \
            __builtin_amdgcn_s_setprio(0);                                       \
        }                                                                        \
    } while (0)

    STG_O(0, 0);
    __syncthreads();
    for (int kt = 0; kt < 15; ++kt) {
        STG_O((kt + 1) & 1, kt + 1);
        CMP_O(kt & 1);
        __syncthreads();
    }
    CMP_O(1);                           // kt = 15

    const int r0 = lk * 4;
#pragma unroll
    for (int mi = 0; mi < 4; ++mi)
#pragma unroll
        for (int ni = 0; ni < 4; ++ni) {
            float* cp = C + (size_t)(bm + wm + mi * 16 + r0) * N + bn + wn + ni * 16 + lr;
#pragma unroll
            for (int r = 0; r < 4; ++r)
                cp[(size_t)r * N] = acc[mi][ni][r];
        }
}

// ------- beta/g projection, split-K partials (fp32): 128 Mtiles x 8 Kslices -------
#define PJS 129   // padded fp32 LDS stride
__global__ __launch_bounds__(256)
void proj_bg_partial(const float* __restrict__ x, const float* __restrict__ Wb,
                     const float* __restrict__ Wa, float* __restrict__ partial) {
    const int m0 = (blockIdx.x >> 3) * 32;   // M-tile
    const int ks = blockIdx.x & 7;           // K-slice
    const int k0 = ks * 128;
    const int tid = threadIdx.x;
    __shared__ float xs[32 * PJS];
    __shared__ float wsh[32 * PJS];
    const int sr = tid >> 3;                 // 0..31
    const int sc = (tid & 7) << 4;           // 0,16,...,112
    const int mi2 = tid >> 3;
    const int n02 = (tid & 7) << 2;          // 0,4,...,28

    {
        const float* xrow = x + (size_t)(m0 + sr) * D_ + k0 + sc;
        const float* wrow = ((sr < 16) ? (Wb + (size_t)sr * D_) : (Wa + (size_t)(sr - 16) * D_)) + k0 + sc;
#pragma unroll
        for (int j = 0; j < 16; j += 4) {
            float4 a = *(const float4*)(xrow + j);
            float4 b = *(const float4*)(wrow + j);
            xs[sr * PJS + sc + j + 0] = a.x; xs[sr * PJS + sc + j + 1] = a.y;
            xs[sr * PJS + sc + j + 2] = a.z; xs[sr * PJS + sc + j + 3] = a.w;
            wsh[sr * PJS + sc + j + 0] = b.x; wsh[sr * PJS + sc + j + 1] = b.y;
            wsh[sr * PJS + sc + j + 2] = b.z; wsh[sr * PJS + sc + j + 3] = b.w;
        }
    }
    __syncthreads();

    float acc[4] = {0.f, 0.f, 0.f, 0.f};
#pragma unroll 8
    for (int kk = 0; kk < 128; ++kk) {
        float av = xs[mi2 * PJS + kk];
#pragma unroll
        for (int j = 0; j < 4; ++j)
            acc[j] = fmaf(av, wsh[(n02 + j) * PJS + kk], acc[j]);
    }
    float* op = partial + (size_t)ks * (4096 * 32) + (size_t)(m0 + mi2) * 32 + n02;
    *(float4*)op = make_float4(acc[0], acc[1], acc[2], acc[3]);
}

__global__ __launch_bounds__(256)
void proj_bg_reduce(const float* __restrict__ partial, const float* __restrict__ dt_bias,
                    const float* __restrict__ A_log,
                    float* __restrict__ beta, float* __restrict__ g) {
    const int gid = blockIdx.x * 256 + threadIdx.x;   // [0, 4096*32)
    const int m = gid >> 5;
    const int n = gid & 31;
    float s = 0.f;
#pragma unroll
    for (int ks = 0; ks < 8; ++ks)
        s += partial[(size_t)ks * (4096 * 32) + gid];
    if (n < 16) {
        beta[(size_t)m * H_ + n] = 1.f / (1.f + expf(-s));
    } else {
        int h = n - 16;
        float spin = s + dt_bias[h];
        float sp = (spin > 20.f) ? spin : log1pf(expf(spin));
        g[(size_t)m * H_ + h] = -expf(A_log[h]) * sp;
    }
}

// ---- causal depthwise conv (K=4) + SiLU: bf16 in, time-tiled x8, bf16 out ----
__global__ __launch_bounds__(256)
void conv_silu_tt(const unsigned short* __restrict__ mixedb,
                  const float* __restrict__ conv_w,
                  unsigned short* __restrict__ qkvb) {
    int idx = blockIdx.x * 256 + threadIdx.x;   // over B*(T/TT)*(CD/4)
    const int cq = idx % (CD_ / 4);
    const int bt8 = idx / (CD_ / 4);
    const int t0 = (bt8 % (T_ / TT)) * TT;
    const int b = bt8 / (T_ / TT);
    const int c0 = cq << 2;
    const unsigned short* base = mixedb + (size_t)(b * T_ + t0) * CD_ + c0;

    float vals[TT + 3][4];
#pragma unroll
    for (int i = 0; i < TT + 3; ++i) {
        int t = t0 + i - 3;
        if (t >= 0) {
            u16x4 m = *(const u16x4*)(base + (ptrdiff_t)(i - 3) * CD_);
            vals[i][0] = bf2f(m.x); vals[i][1] = bf2f(m.y);
            vals[i][2] = bf2f(m.z); vals[i][3] = bf2f(m.w);
        } else {
            vals[i][0] = vals[i][1] = vals[i][2] = vals[i][3] = 0.f;
        }
    }
    const float4* wp = (const float4*)(conv_w + (size_t)c0 * 4);
    float4 w[4] = {wp[0], wp[1], wp[2], wp[3]};

    unsigned short* outp = qkvb + (size_t)(b * T_ + t0) * CD_ + c0;
#pragma unroll
    for (int tt = 0; tt < TT; ++tt) {
        u16x4 r;
        float s0 = vals[tt + 3][0] * w[0].w + vals[tt + 2][0] * w[0].z
                 + vals[tt + 1][0] * w[0].y + vals[tt + 0][0] * w[0].x;
        float s1 = vals[tt + 3][1] * w[1].w + vals[tt + 2][1] * w[1].z
                 + vals[tt + 1][1] * w[1].y + vals[tt + 0][1] * w[1].x;
        float s2 = vals[tt + 3][2] * w[2].w + vals[tt + 2][2] * w[2].z
                 + vals[tt + 1][2] * w[2].y + vals[tt + 0][2] * w[2].x;
        float s3 = vals[tt + 3][3] * w[3].w + vals[tt + 2][3] * w[3].z
                 + vals[tt + 1][3] * w[3].y + vals[tt + 0][3] * w[3].x;
        r.x = f2bf(s0 / (1.f + expf(-s0)));
        r.y = f2bf(s1 / (1.f + expf(-s1)));
        r.z = f2bf(s2 / (1.f + expf(-s2)));
        r.w = f2bf(s3 / (1.f + expf(-s3)));
        *(u16x4*)(outp + (size_t)tt * CD_) = r;
    }
}

// ------------ phase 1 (MFMA): per-chunk dS^T[v][d], cum, a_c; k-l2norm fused --
__global__ __launch_bounds__(256)
void chunk_phase1(const unsigned short* __restrict__ qkvb,
                  const float* __restrict__ beta, const float* __restrict__ gg,
                  float* __restrict__ dST, float* __restrict__ cum,
                  float* __restrict__ ac) {
    const int cid = blockIdx.x;           // (b*H+h)*NC + c
    const int c = cid & (NC_ - 1);
    const int bh = cid >> 5;
    const int b = bh >> 4, h = bh & 15;
    const int tid = threadIdx.x;
    const int wave = tid >> 6, lane = tid & 63;
    const int t0 = c * L_;

    __shared__ __align__(16) short kT[64 * TS];   // [d][s], RAW k
    __shared__ __align__(16) short vT[64 * TS];   // [v][s], weighted (beta*decay/||k||)
    __shared__ float cumS[64], wS[64];
    __shared__ float ksumP[4][64];                // per-wave k sumsq partials

    const unsigned short* rowp = qkvb + (size_t)(b * T_ + t0 + lane) * CD_ + h * HD_ + wave * 16;
    bf16x8 k0 = *(const bf16x8*)(rowp + D_);
    bf16x8 k1 = *(const bf16x8*)(rowp + D_ + 8);
    bf16x8 v0 = *(const bf16x8*)(rowp + 2 * D_);
    bf16x8 v1 = *(const bf16x8*)(rowp + 2 * D_ + 8);

    {   // partial sum of squares of this wave's 16 k-columns for timestep s=lane
        float ks = 0.f;
#pragma unroll
        for (int j = 0; j < 8; ++j) {
            float a = bf2f((unsigned short)k0[j]); ks = fmaf(a, a, ks);
            float bq = bf2f((unsigned short)k1[j]); ks = fmaf(bq, bq, ks);
        }
        ksumP[wave][lane] = ks;
    }

    if (wave == 0) {   // parallel inclusive scan of g over the 64 timesteps
        float s = gg[(size_t)(b * T_ + t0 + lane) * H_ + h];
#pragma unroll
        for (int off = 1; off < 64; off <<= 1) {
            float up = __shfl_up(s, off, 64);
            if (lane >= off) s += up;
        }
        cumS[lane] = s;
        float cend = __shfl(s, 63, 64);
        wS[lane] = expf(cend - s) * beta[(size_t)(b * T_ + t0 + lane) * H_ + h];
        cum[(size_t)bh * T_ + t0 + lane] = s;
        if (lane == 63) ac[cid] = expf(cend);
    }
    __syncthreads();
    const float kn = rsqrtf(ksumP[0][lane] + ksumP[1][lane] + ksumP[2][lane]
                            + ksumP[3][lane] + 1e-6f);
    const float w = wS[lane] * kn;     // fold 1/||k|| into the v-weight
#pragma unroll
    for (int j = 0; j < 8; ++j) {
        kT[(wave * 16 + j) * TS + lane] = k0[j];
        kT[(wave * 16 + 8 + j) * TS + lane] = k1[j];
        vT[(wave * 16 + j) * TS + lane] = f2bf(bf2f((unsigned short)v0[j]) * w);
        vT[(wave * 16 + 8 + j) * TS + lane] = f2bf(bf2f((unsigned short)v1[j]) * w);
    }
    __syncthreads();

    const int lr = lane & 15, lk = lane >> 4;
    f32x4 acc[4] = {};
    const short* pA = vT + (wave * 16 + lr) * TS + lk * 8;
#pragma unroll
    for (int kk = 0; kk < 2; ++kk) {
        bf16x8 a = *(const bf16x8*)(pA + kk * 32);
#pragma unroll
        for (int n = 0; n < 4; ++n) {
            bf16x8 bfr = *(const bf16x8*)(kT + (n * 16 + lr) * TS + lk * 8 + kk * 32);
            acc[n] = __builtin_amdgcn_mfma_f32_16x16x32_bf16(a, bfr, acc[n], 0, 0, 0);
        }
    }
#pragma unroll
    for (int n = 0; n < 4; ++n) {
        float* op = dST + (size_t)cid * 4096 + (wave * 16 + lk * 4) * 64 + n * 16 + lr;
#pragma unroll
        for (int r = 0; r < 4; ++r)
            op[r * 64] = acc[n][r];
    }
}

// ---------------- phase 2: scan over chunks, IN PLACE (dST -> states) --------
__global__ __launch_bounds__(256)
void chunk_phase2(float* __restrict__ dST, const float* __restrict__ ac) {
    const int gid = blockIdx.x * 256 + threadIdx.x;  // B*H*4096 = 131072
    const int bh = gid >> 12;
    const int e = gid & 4095;
    float s = 0.f;
    for (int c = 0; c < NC_; ++c) {
        size_t off = (size_t)(bh * NC_ + c) * 4096 + e;
        float tmp = dST[off];
        dST[off] = s;
        s = fmaf(ac[bh * NC_ + c], s, tmp);
    }
}

// -- phase 3 (MFMA): O = exp(ct)*Q*S_in + P*V; q/k-l2norm + gated-RMSNorm fused --
__global__ __launch_bounds__(256)
void chunk_phase3(const unsigned short* __restrict__ qkvb,
                  const float* __restrict__ beta, const float* __restrict__ cum,
                  const float* __restrict__ states,   // dST layout [cid][v][d] fp32
                  const unsigned short* __restrict__ zb,
                  unsigned short* __restrict__ normb) {
    const int cid = blockIdx.x;
    const int c = cid & (NC_ - 1);
    const int bh = cid >> 5;
    const int b = bh >> 4, h = bh & 15;
    const int tid = threadIdx.x;
    const int wave = tid >> 6, lane = tid & 63;
    const int t0 = c * L_;

    __shared__ __align__(16) short vT[64 * TS];   // [v][s]
    __shared__ __align__(16) short sT[64 * TS];   // S_in^T bf16 [v][d]
    __shared__ __align__(16) short pS[64 * TS];   // P [t][s] bf16
    __shared__ float cumS[64], betaS[64];
    __shared__ float invq[64], invk[64];

    {   // stage vT (transpose)
        const unsigned short* rowp = qkvb + (size_t)(b * T_ + t0 + lane) * CD_ + 2 * D_ + h * HD_ + wave * 16;
        bf16x8 v0 = *(const bf16x8*)rowp;
        bf16x8 v1 = *(const bf16x8*)(rowp + 8);
#pragma unroll
        for (int j = 0; j < 8; ++j) {
            vT[(wave * 16 + j) * TS + lane] = v0[j];
            vT[(wave * 16 + 8 + j) * TS + lane] = v1[j];
        }
    }
    {   // stage sT (fp32 -> bf16)
        const float* sp = states + (size_t)cid * 4096 + (tid >> 2) * 64 + (tid & 3) * 16;
        short* dp = sT + (tid >> 2) * TS + (tid & 3) * 16;
#pragma unroll
        for (int j = 0; j < 16; j += 4) {
            float4 f = *(const float4*)(sp + j);
            dp[j] = f2bf(f.x); dp[j + 1] = f2bf(f.y);
            dp[j + 2] = f2bf(f.z); dp[j + 3] = f2bf(f.w);
        }
    }
    {   // per-row l2norm factors for q and k (4 threads per row)
        int row = tid >> 2;
        int seg = (tid & 3) << 4;   // 0,16,32,48
        const unsigned short* qr = qkvb + (size_t)(b * T_ + t0 + row) * CD_ + h * HD_ + seg;
        bf16x8 a0 = *(const bf16x8*)qr;
        bf16x8 a1 = *(const bf16x8*)(qr + 8);
        float sq = 0.f;
#pragma unroll
        for (int j = 0; j < 8; ++j) {
            float v = bf2f((unsigned short)a0[j]); sq = fmaf(v, v, sq);
            v = bf2f((unsigned short)a1[j]); sq = fmaf(v, v, sq);
        }
        sq += __shfl_xor(sq, 1, 64);
        sq += __shfl_xor(sq, 2, 64);
        const unsigned short* kr = qr + D_;
        bf16x8 b0 = *(const bf16x8*)kr;
        bf16x8 b1 = *(const bf16x8*)(kr + 8);
        float sk = 0.f;
#pragma unroll
        for (int j = 0; j < 8; ++j) {
            float v = bf2f((unsigned short)b0[j]); sk = fmaf(v, v, sk);
            v = bf2f((unsigned short)b1[j]); sk = fmaf(v, v, sk);
        }
        sk += __shfl_xor(sk, 1, 64);
        sk += __shfl_xor(sk, 2, 64);
        if ((tid & 3) == 0) {
            invq[row] = 0.125f * rsqrtf(sq + 1e-6f);   // includes HD^-0.5
            invk[row] = rsqrtf(sk + 1e-6f);
        }
    }
    if (tid < 64) {
        cumS[tid] = cum[(size_t)bh * T_ + t0 + tid];
        betaS[tid] = beta[(size_t)(b * T_ + t0 + tid) * H_ + h];
    }
    __syncthreads();

    const int lr = lane & 15, lk = lane >> 4;
    const unsigned short* qrow = qkvb + (size_t)(b * T_ + t0 + wave * 16 + lr) * CD_ + h * HD_;
    bf16x8 qf0 = *(const bf16x8*)(qrow + lk * 8);
    bf16x8 qf1 = *(const bf16x8*)(qrow + 32 + lk * 8);

    // QK^T on RAW q,k
    f32x4 pacc[4] = {};
#pragma unroll
    for (int n = 0; n < 4; ++n) {
        const unsigned short* krow = qkvb + (size_t)(b * T_ + t0 + n * 16 + lr) * CD_ + D_ + h * HD_;
        bf16x8 b0 = *(const bf16x8*)(krow + lk * 8);
        bf16x8 b1 = *(const bf16x8*)(krow + 32 + lk * 8);
        pacc[n] = __builtin_amdgcn_mfma_f32_16x16x32_bf16(qf0, b0, pacc[n], 0, 0, 0);
        pacc[n] = __builtin_amdgcn_mfma_f32_16x16x32_bf16(qf1, b1, pacc[n], 0, 0, 0);
    }
    // decay + mask + beta + norms -> pS (bf16)
#pragma unroll
    for (int n = 0; n < 4; ++n) {
        int s = n * 16 + lr;
        float cs = cumS[s], bsk = betaS[s] * invk[s];
#pragma unroll
        for (int r = 0; r < 4; ++r) {
            int t = wave * 16 + lk * 4 + r;
            float pv = (s <= t) ? expf(cumS[t] - cs) * bsk * pacc[n][r] * invq[t] : 0.f;
            pS[t * TS + s] = f2bf(pv);
        }
    }
    __syncthreads();

    // O = Q * S_in^T-frags (raw q, scaled after)
    f32x4 oacc[4] = {};
#pragma unroll
    for (int n = 0; n < 4; ++n) {
        const short* srow = sT + (n * 16 + lr) * TS + lk * 8;
        bf16x8 b0 = *(const bf16x8*)srow;
        bf16x8 b1 = *(const bf16x8*)(srow + 32);
        oacc[n] = __builtin_amdgcn_mfma_f32_16x16x32_bf16(qf0, b0, oacc[n], 0, 0, 0);
        oacc[n] = __builtin_amdgcn_mfma_f32_16x16x32_bf16(qf1, b1, oacc[n], 0, 0, 0);
    }
    float qsc[4];
#pragma unroll
    for (int r = 0; r < 4; ++r) {
        int t = wave * 16 + lk * 4 + r;
        qsc[r] = expf(cumS[t]) * invq[t];
    }
#pragma unroll
    for (int n = 0; n < 4; ++n)
#pragma unroll
        for (int r = 0; r < 4; ++r) oacc[n][r] *= qsc[r];
    // + P * V
    const short* prow = pS + (wave * 16 + lr) * TS + lk * 8;
    bf16x8 pf0 = *(const bf16x8*)prow;
    bf16x8 pf1 = *(const bf16x8*)(prow + 32);
#pragma unroll
    for (int n = 0; n < 4; ++n) {
        const short* vrow = vT + (n * 16 + lr) * TS + lk * 8;
        bf16x8 b0 = *(const bf16x8*)vrow;
        bf16x8 b1 = *(const bf16x8*)(vrow + 32);
        oacc[n] = __builtin_amdgcn_mfma_f32_16x16x32_bf16(pf0, b0, oacc[n], 0, 0, 0);
        oacc[n] = __builtin_amdgcn_mfma_f32_16x16x32_bf16(pf1, b1, oacc[n], 0, 0, 0);
    }

    // fused gated RMSNorm over head dim + bf16 store
#pragma unroll
    for (int r = 0; r < 4; ++r) {
        int t = wave * 16 + lk * 4 + r;
        float ss = 0.f;
#pragma unroll
        for (int n = 0; n < 4; ++n) ss = fmaf(oacc[n][r], oacc[n][r], ss);
        ss += __shfl_xor(ss, 1, 64);
        ss += __shfl_xor(ss, 2, 64);
        ss += __shfl_xor(ss, 4, 64);
        ss += __shfl_xor(ss, 8, 64);
        float inv = rsqrtf(ss * (1.f / 64.f) + 1e-6f);
        size_t rowoff = (size_t)(b * T_ + t0 + t) * D_ + h * HD_;
#pragma unroll
        for (int n = 0; n < 4; ++n) {
            float zv = bf2f(zb[rowoff + n * 16 + lr]);
            float sz = zv / (1.f + expf(-zv));
            normb[rowoff + n * 16 + lr] = f2bf(oacc[n][r] * inv * sz);
        }
    }
}

extern "C" void kernel_launch(void* const* d_in, const int* in_sizes, int n_in,
                              void* d_out, int out_size, void* d_ws, size_t ws_size,
                              hipStream_t stream) {
    const float* x       = (const float*)d_in[0];
    const float* W_qkv   = (const float*)d_in[1];
    const float* conv_w  = (const float*)d_in[2];
    const float* W_z     = (const float*)d_in[3];
    const float* W_b     = (const float*)d_in[4];
    const float* W_a     = (const float*)d_in[5];
    const float* dt_bias = (const float*)d_in[6];
    const float* A_log   = (const float*)d_in[7];
    const float* W_out   = (const float*)d_in[8];
    float* out = (float*)d_out;

    float* ws = (float*)d_ws;
    // Region A: mixedb (bf16) until conv; overlays after:
    unsigned short* mixedb = (unsigned short*)ws;              // 12.6M bf16 (25 MB)
    float* dST    = ws;                        // 4M floats (ph1 -> ph2 in-place -> ph3)
    unsigned short* normb = (unsigned short*)(ws + 4194304);   // 4.2M bf16 (ph3 output)
    float* betab  = ws + 8388608;              // 65,536
    float* gb     = ws + 8454144;              // 65,536
    float* cum    = ws + 8519680;              // 65,536
    float* ac     = ws + 8585216;              // 1,024
    unsigned short* Woutb = (unsigned short*)(ws + 8586240);   // 1M bf16
    // Region B: xb/Wqkvb/Wzb pre-conv; qkvb after
    unsigned short* xb    = (unsigned short*)(ws + 12582912);  // 4M bf16
    unsigned short* Wqkvb = (unsigned short*)(ws + 14680064);  // 3M bf16 (cat head)
    unsigned short* Wzb   = (unsigned short*)(ws + 16252928);  // 1M bf16 (cat tail)
    unsigned short* qkvb  = (unsigned short*)(ws + 12582912);  // 12.6M bf16
    // Region C
    unsigned short* zb    = (unsigned short*)(ws + 18874368);  // 4M bf16
    float* bgpart = ws + 23068672;             // 1M floats (4 MB)

    const int M = B_ * T_;                     // 4096
    dim3 blk(256);

    cvt_all<<<dim3(9216), blk, 0, stream>>>(x, W_qkv, W_z, W_out, xb, Wqkvb, Wzb, Woutb);

    gemm_qkvz256<<<dim3(256), dim3(512), 131072, stream>>>(xb, Wqkvb, mixedb, zb);

    conv_silu_tt<<<dim3(B_ * (T_ / TT) * (CD_ / 4) / 256), blk, 0, stream>>>(mixedb, conv_w, qkvb);

    proj_bg_partial<<<dim3(1024), blk, 0, stream>>>(x, W_b, W_a, bgpart);
    proj_bg_reduce<<<dim3(512), blk, 0, stream>>>(bgpart, dt_bias, A_log, betab, gb);

    chunk_phase1<<<dim3(B_ * H_ * NC_), blk, 0, stream>>>(qkvb, betab, gb, dST, cum, ac);
    chunk_phase2<<<dim3(B_ * H_ * 4096 / 256), blk, 0, stream>>>(dST, ac);
    chunk_phase3<<<dim3(B_ * H_ * NC_), blk, 0, stream>>>(qkvb, betab, cum, dST, zb, normb);

    gemm_out<<<dim3(256), blk, 0, stream>>>(normb, Woutb, out);
}